// Round 1
// baseline (1907.346 us; speedup 1.0000x reference)
//
#include <hip/hip_runtime.h>
#include <hip/hip_bf16.h>

// Problem constants (from reference): B=8, T=2048, C=384, H=6, Dh=64
constexpr int B_ = 8;
constexpr int T_ = 2048;
constexpr int C_ = 384;
constexpr int H_ = 6;
constexpr int D_ = 64;

typedef float f4 __attribute__((ext_vector_type(4)));
typedef unsigned int u32;

__device__ __forceinline__ unsigned short f2bf(float f) {
  u32 u = __float_as_uint(f);
  u32 r = (u + 0x7FFFu + ((u >> 16) & 1u)) >> 16;  // round-to-nearest-even
  return (unsigned short)r;
}
__device__ __forceinline__ float bflo(u32 u) { return __uint_as_float(u << 16); }
__device__ __forceinline__ float bfhi(u32 u) { return __uint_as_float(u & 0xFFFF0000u); }

// ---------------------------------------------------------------------------
// Kernel 1: QKV projection. x[b,t,:] (fp32) x Wq/Wk/Wv[h] ([C,Dh]) -> bf16
// Q/K/V stored [B,H,T,Dh]. Grid: B*(T/64) blocks of 256 threads.
// LDS: x tile [64][388] fp32 (pad 388 -> 2-way bank conflict max, free).
// ---------------------------------------------------------------------------
__global__ __launch_bounds__(256) void qkv_kernel(
    const float* __restrict__ x, const float* __restrict__ Wq,
    const float* __restrict__ Wk, const float* __restrict__ Wv,
    unsigned short* __restrict__ Qb, unsigned short* __restrict__ Kb,
    unsigned short* __restrict__ Vb) {
  __shared__ float xs[64 * 388];
  const int tid = threadIdx.x;
  const int b = blockIdx.x >> 5;          // T/64 = 32 tiles per batch
  const int t0 = (blockIdx.x & 31) << 6;

  const float* xg = x + ((size_t)(b * T_ + t0)) * C_;
  for (int j = tid; j < 64 * 96; j += 256) {   // 96 float4 per 384-float row
    int row = j / 96, c4 = j % 96;
    f4 v = *(const f4*)(xg + (size_t)row * C_ + c4 * 4);
    *(f4*)(xs + row * 388 + c4 * 4) = v;
  }
  __syncthreads();

  const int cg = tid & 15;   // 4 output cols: cg*4 + j
  const int rg = tid >> 4;   // 4 rows: rg*4 + i

  for (int h = 0; h < H_; ++h) {
    const float* wq = Wq + (size_t)h * C_ * D_;
    const float* wk = Wk + (size_t)h * C_ * D_;
    const float* wv = Wv + (size_t)h * C_ * D_;
    float aq[4][4] = {}, ak[4][4] = {}, avv[4][4] = {};
    for (int k4 = 0; k4 < 96; ++k4) {
      f4 a[4];
#pragma unroll
      for (int i = 0; i < 4; ++i)
        a[i] = *(const f4*)(xs + (rg * 4 + i) * 388 + k4 * 4);
#pragma unroll
      for (int kk = 0; kk < 4; ++kk) {
        const int k = k4 * 4 + kk;
        f4 qw = *(const f4*)(wq + (size_t)k * D_ + cg * 4);
        f4 kw = *(const f4*)(wk + (size_t)k * D_ + cg * 4);
        f4 vw = *(const f4*)(wv + (size_t)k * D_ + cg * 4);
#pragma unroll
        for (int i = 0; i < 4; ++i) {
          const float av_ = a[i][kk];
#pragma unroll
          for (int j = 0; j < 4; ++j) {
            aq[i][j] += av_ * qw[j];
            ak[i][j] += av_ * kw[j];
            avv[i][j] += av_ * vw[j];
          }
        }
      }
    }
#pragma unroll
    for (int i = 0; i < 4; ++i) {
      const size_t base =
          ((size_t)((b * H_ + h) * T_ + t0 + rg * 4 + i)) * D_ + cg * 4;
      uint2 pq, pk, pv;
      pq.x = (u32)f2bf(aq[i][0]) | ((u32)f2bf(aq[i][1]) << 16);
      pq.y = (u32)f2bf(aq[i][2]) | ((u32)f2bf(aq[i][3]) << 16);
      pk.x = (u32)f2bf(ak[i][0]) | ((u32)f2bf(ak[i][1]) << 16);
      pk.y = (u32)f2bf(ak[i][2]) | ((u32)f2bf(ak[i][3]) << 16);
      pv.x = (u32)f2bf(avv[i][0]) | ((u32)f2bf(avv[i][1]) << 16);
      pv.y = (u32)f2bf(avv[i][2]) | ((u32)f2bf(avv[i][3]) << 16);
      *(uint2*)(Qb + base) = pq;
      *(uint2*)(Kb + base) = pk;
      *(uint2*)(Vb + base) = pv;
    }
  }
}

// ---------------------------------------------------------------------------
// Kernel 2: causal flash attention, fp32 compute from bf16 Q/K/V.
// Grid: B*H*(T/64) blocks of 256 threads. Per block: one (b,h,64-row q tile).
// Online softmax. S-phase cols strided (cg+16j); O cols contiguous (cg*4+j).
// ---------------------------------------------------------------------------
__global__ __launch_bounds__(256) void attn_kernel(
    const unsigned short* __restrict__ Qb, const unsigned short* __restrict__ Kb,
    const unsigned short* __restrict__ Vb, float* __restrict__ attn) {
  __shared__ float Qs[64 * 68];
  __shared__ float Ks[64 * 68];
  __shared__ float Vs[64 * 68];
  __shared__ float Ps[64 * 68];

  const int tid = threadIdx.x;
  const int bx = blockIdx.x;
  const int qi = bx & 31;
  const int bh = bx >> 5;
  const int h = bh % H_;
  const int b = bh / H_;
  const int r0 = qi * 64;
  const size_t headbase = ((size_t)(b * H_ + h)) * T_ * D_;

  // Load Q tile, pre-scaled by Dh^-0.5 = 0.125
  {
    const uint4* qg = (const uint4*)(Qb + headbase + (size_t)r0 * D_);
    for (int j = tid; j < 512; j += 256) {
      uint4 u = qg[j];
      int row = j >> 3, col = (j & 7) * 8;
      float* d = Qs + row * 68 + col;
      d[0] = bflo(u.x) * 0.125f; d[1] = bfhi(u.x) * 0.125f;
      d[2] = bflo(u.y) * 0.125f; d[3] = bfhi(u.y) * 0.125f;
      d[4] = bflo(u.z) * 0.125f; d[5] = bfhi(u.z) * 0.125f;
      d[6] = bflo(u.w) * 0.125f; d[7] = bfhi(u.w) * 0.125f;
    }
  }

  const int cg = tid & 15;
  const int rg = tid >> 4;   // thread's rows: rg + 16*i (i<4), same-wave group

  float m[4], l[4];
  float acc[4][4] = {};   // O[rg+16i][cg*4+j]
#pragma unroll
  for (int i = 0; i < 4; ++i) { m[i] = -1e30f; l[i] = 0.f; }

  for (int jt = 0; jt <= qi; ++jt) {
    __syncthreads();   // previous tile's reads done before overwrite
    {
      const uint4* kg = (const uint4*)(Kb + headbase + (size_t)(jt * 64) * D_);
      const uint4* vg = (const uint4*)(Vb + headbase + (size_t)(jt * 64) * D_);
      for (int j = tid; j < 512; j += 256) {
        uint4 u = kg[j];
        int row = j >> 3, col = (j & 7) * 8;
        float* d = Ks + row * 68 + col;
        d[0] = bflo(u.x); d[1] = bfhi(u.x); d[2] = bflo(u.y); d[3] = bfhi(u.y);
        d[4] = bflo(u.z); d[5] = bfhi(u.z); d[6] = bflo(u.w); d[7] = bfhi(u.w);
        u = vg[j];
        d = Vs + row * 68 + col;
        d[0] = bflo(u.x); d[1] = bfhi(u.x); d[2] = bflo(u.y); d[3] = bfhi(u.y);
        d[4] = bflo(u.z); d[5] = bfhi(u.z); d[6] = bflo(u.w); d[7] = bfhi(u.w);
      }
    }
    __syncthreads();

    // S = (Q*scale) @ K^T : thread owns rows rg+16i, cols cg+16j
    float s[4][4] = {};
    for (int k4 = 0; k4 < 16; ++k4) {
      f4 q[4], kk[4];
#pragma unroll
      for (int i = 0; i < 4; ++i)
        q[i] = *(const f4*)(Qs + (rg + 16 * i) * 68 + k4 * 4);
#pragma unroll
      for (int j = 0; j < 4; ++j)
        kk[j] = *(const f4*)(Ks + (cg + 16 * j) * 68 + k4 * 4);
#pragma unroll
      for (int i = 0; i < 4; ++i)
#pragma unroll
        for (int j = 0; j < 4; ++j) {
          s[i][j] += q[i][0] * kk[j][0];
          s[i][j] += q[i][1] * kk[j][1];
          s[i][j] += q[i][2] * kk[j][2];
          s[i][j] += q[i][3] * kk[j][3];
        }
    }

    // Causal mask (only diagonal tile partially masked)
    if (jt == qi) {
#pragma unroll
      for (int i = 0; i < 4; ++i)
#pragma unroll
        for (int j = 0; j < 4; ++j)
          if (cg + 16 * j > rg + 16 * i) s[i][j] = -1e30f;
    }

    // Online softmax update (rows live across the 16 cg lanes of this rg)
#pragma unroll
    for (int i = 0; i < 4; ++i) {
      float pm = fmaxf(fmaxf(s[i][0], s[i][1]), fmaxf(s[i][2], s[i][3]));
      pm = fmaxf(pm, __shfl_xor(pm, 1));
      pm = fmaxf(pm, __shfl_xor(pm, 2));
      pm = fmaxf(pm, __shfl_xor(pm, 4));
      pm = fmaxf(pm, __shfl_xor(pm, 8));
      const float mn = fmaxf(m[i], pm);
      const float f = __expf(m[i] - mn);
      float rs = 0.f;
#pragma unroll
      for (int j = 0; j < 4; ++j) {
        const float p = __expf(s[i][j] - mn);
        Ps[(rg + 16 * i) * 68 + cg + 16 * j] = p;
        rs += p;
      }
      rs += __shfl_xor(rs, 1);
      rs += __shfl_xor(rs, 2);
      rs += __shfl_xor(rs, 4);
      rs += __shfl_xor(rs, 8);
      l[i] = l[i] * f + rs;
      m[i] = mn;
#pragma unroll
      for (int j = 0; j < 4; ++j) acc[i][j] *= f;
    }
    __syncthreads();   // Ps visible (conservative; rows are wave-local)

    // O += P @ V : thread owns rows rg+16i, cols cg*4+j (contiguous)
    for (int c4 = 0; c4 < 16; ++c4) {
      f4 p[4];
#pragma unroll
      for (int i = 0; i < 4; ++i)
        p[i] = *(const f4*)(Ps + (rg + 16 * i) * 68 + c4 * 4);
#pragma unroll
      for (int cc = 0; cc < 4; ++cc) {
        f4 v = *(const f4*)(Vs + (c4 * 4 + cc) * 68 + cg * 4);
#pragma unroll
        for (int i = 0; i < 4; ++i) {
          const float pv = p[i][cc];
#pragma unroll
          for (int j = 0; j < 4; ++j) acc[i][j] += pv * v[j];
        }
      }
    }
  }

  // Epilogue: O /= l, write to attn[b, t, h*64 + d] (head-concat layout)
#pragma unroll
  for (int i = 0; i < 4; ++i) {
    const float inv = 1.f / l[i];
    f4 o;
#pragma unroll
    for (int j = 0; j < 4; ++j) o[j] = acc[i][j] * inv;
    const int row = r0 + rg + 16 * i;
    *(f4*)(attn + ((size_t)(b * T_ + row)) * C_ + h * 64 + cg * 4) = o;
  }
}

// ---------------------------------------------------------------------------
// Kernel 3: output projection. out = attn @ Wp + bp. Grid: B*(T/64) blocks.
// ---------------------------------------------------------------------------
__global__ __launch_bounds__(256) void proj_kernel(
    const float* __restrict__ attn, const float* __restrict__ Wp,
    const float* __restrict__ bp, float* __restrict__ out) {
  __shared__ float as_[64 * 388];
  const int tid = threadIdx.x;
  const int b = blockIdx.x >> 5;
  const int t0 = (blockIdx.x & 31) << 6;

  const float* ag = attn + ((size_t)(b * T_ + t0)) * C_;
  for (int j = tid; j < 64 * 96; j += 256) {
    int row = j / 96, c4 = j % 96;
    f4 v = *(const f4*)(ag + (size_t)row * C_ + c4 * 4);
    *(f4*)(as_ + row * 388 + c4 * 4) = v;
  }
  __syncthreads();

  const int cg = tid & 15;
  const int rg = tid >> 4;

  for (int ch = 0; ch < 6; ++ch) {        // 6 chunks of 64 output cols
    float acc[4][4] = {};
    for (int k4 = 0; k4 < 96; ++k4) {
      f4 a[4];
#pragma unroll
      for (int i = 0; i < 4; ++i)
        a[i] = *(const f4*)(as_ + (rg * 4 + i) * 388 + k4 * 4);
#pragma unroll
      for (int kk = 0; kk < 4; ++kk) {
        const int k = k4 * 4 + kk;
        f4 w = *(const f4*)(Wp + (size_t)k * C_ + ch * 64 + cg * 4);
#pragma unroll
        for (int i = 0; i < 4; ++i) {
          const float av_ = a[i][kk];
#pragma unroll
          for (int j = 0; j < 4; ++j) acc[i][j] += av_ * w[j];
        }
      }
    }
    f4 bb = *(const f4*)(bp + ch * 64 + cg * 4);
#pragma unroll
    for (int i = 0; i < 4; ++i) {
      f4 o;
#pragma unroll
      for (int j = 0; j < 4; ++j) o[j] = acc[i][j] + bb[j];
      *(f4*)(out + ((size_t)(b * T_ + t0 + rg * 4 + i)) * C_ + ch * 64 + cg * 4) = o;
    }
  }
}

// ---------------------------------------------------------------------------
extern "C" void kernel_launch(void* const* d_in, const int* in_sizes, int n_in,
                              void* d_out, int out_size, void* d_ws, size_t ws_size,
                              hipStream_t stream) {
  (void)in_sizes; (void)n_in; (void)out_size; (void)ws_size;
  const float* x  = (const float*)d_in[0];
  const float* Wq = (const float*)d_in[1];
  const float* Wk = (const float*)d_in[2];
  const float* Wv = (const float*)d_in[3];
  const float* Wp = (const float*)d_in[4];
  const float* bp = (const float*)d_in[5];
  float* out = (float*)d_out;

  // Workspace layout: Q,K,V bf16 [B,H,T,Dh] then attn fp32 [B,T,C] = 63 MB
  const size_t nqkv = (size_t)B_ * H_ * T_ * D_;   // 6,291,456
  unsigned short* Qb = (unsigned short*)d_ws;
  unsigned short* Kb = Qb + nqkv;
  unsigned short* Vb = Kb + nqkv;
  float* attn = (float*)(Vb + nqkv);

  qkv_kernel<<<dim3(B_ * (T_ / 64)), dim3(256), 0, stream>>>(x, Wq, Wk, Wv, Qb, Kb, Vb);
  attn_kernel<<<dim3(B_ * H_ * (T_ / 64)), dim3(256), 0, stream>>>(Qb, Kb, Vb, attn);
  proj_kernel<<<dim3(B_ * (T_ / 64)), dim3(256), 0, stream>>>(attn, Wp, bp, out);
}

// Round 2
// 264.018 us; speedup vs baseline: 7.2243x; 7.2243x over previous
//
#include <hip/hip_runtime.h>

// B=8, T=2048, C=384, H=6, Dh=64
constexpr int T_ = 2048;
constexpr int C_ = 384;
constexpr int H_ = 6;
constexpr int D_ = 64;

typedef unsigned int u32;
typedef unsigned short u16;
typedef __attribute__((ext_vector_type(4))) float f32x4;
typedef __attribute__((ext_vector_type(8))) short bf16x8;

__device__ __forceinline__ u32 f2bf(float f) {
  u32 u = __float_as_uint(f);
  return (u + 0x7FFFu + ((u >> 16) & 1u)) >> 16;  // RNE
}
__device__ __forceinline__ u32 pk2(float a, float b) {
  return f2bf(a) | (f2bf(b) << 16);
}
// MFMA A/B fragment from padded LDS: 4 bf16 at p, 4 bf16 at p+16 elems.
// k-map kappa(g,j) = g*4 + (j&3) + 16*(j>>2): consistent for A and B, so the
// per-slot pairing cancels and any bijective map is correct.
__device__ __forceinline__ bf16x8 ldsfrag(const u16* p) {
  bf16x8 r;
  *(uint2*)&r = *(const uint2*)p;
  *((uint2*)&r + 1) = *(const uint2*)(p + 16);
  return r;
}
__device__ __forceinline__ bf16x8 u4bf(uint4 u) {
  bf16x8 r; *(uint4*)&r = u; return r;
}

// ---------------------------------------------------------------------------
// Convert weights to bf16, TRANSPOSED [n][k] so GEMM B-frags read contiguous k.
// Wt[1152][384]: n = mat*384 + h*64 + d, k = c.   Wpt[384][384]: n=outcol, k=c.
// ---------------------------------------------------------------------------
__global__ __launch_bounds__(256) void convert_kernel(
    const float* __restrict__ Wq, const float* __restrict__ Wk,
    const float* __restrict__ Wv, const float* __restrict__ Wp,
    u16* __restrict__ Wt, u16* __restrict__ Wpt) {
  int id = blockIdx.x * 256 + threadIdx.x;
  if (id < 110592) {                       // Wt: 1152*384/4
    int n = id / 96, c0 = (id % 96) * 4;
    int mat = n / 384, nn = n % 384, h = nn >> 6, d = nn & 63;
    const float* W = (mat == 0) ? Wq : ((mat == 1) ? Wk : Wv);
    const float* s = W + (size_t)(h * C_ + c0) * D_ + d;   // stride D_ over c
    uint2 o; o.x = pk2(s[0], s[64]); o.y = pk2(s[128], s[192]);
    *(uint2*)&Wt[(size_t)n * 384 + c0] = o;
  } else {                                 // Wpt: 384*384/4
    int id2 = id - 110592;
    int n = id2 / 96, c0 = (id2 % 96) * 4;
    const float* s = Wp + (size_t)c0 * C_ + n;             // stride C_ over c
    uint2 o; o.x = pk2(s[0], s[384]); o.y = pk2(s[768], s[1152]);
    *(uint2*)&Wpt[(size_t)n * 384 + c0] = o;
  }
}

// ---------------------------------------------------------------------------
// QKV GEMM (MFMA): xb tile [64 x 384] (cvt fp32->bf16 on stage) @ Wt chunks.
// Grid: (16384/64) * 6 blocks; ntile 0-1 -> Q, 2-3 -> K, 4-5 -> V (transposed).
// ---------------------------------------------------------------------------
__global__ __launch_bounds__(256) void qkv_mfma_kernel(
    const float* __restrict__ x, const u16* __restrict__ Wt,
    u16* __restrict__ Qb, u16* __restrict__ Kb, u16* __restrict__ Vtb) {
  __shared__ u16 xs[64 * 392];   // pad 392: frag reads <=2-way bank alias
  __shared__ u16 wsh[192 * 72];
  const int tid = threadIdx.x;
  const int nt = blockIdx.x % 6, mt = blockIdx.x / 6;
  const int m0 = mt * 64, n0 = nt * 192, mat = nt >> 1;

  for (int idx = tid; idx < 6144; idx += 256) {
    int row = idx / 96, c4 = (idx % 96) * 4;
    f32x4 v = *(const f32x4*)(x + (size_t)(m0 + row) * C_ + c4);
    uint2 o; o.x = pk2(v[0], v[1]); o.y = pk2(v[2], v[3]);
    *(uint2*)&xs[row * 392 + c4] = o;
  }
  __syncthreads();

  const int l = tid & 63, w = tid >> 6, g = l >> 4, ql = l & 15;
  const int rowm = w * 16 + ql;
  f32x4 acc[12];
#pragma unroll
  for (int i = 0; i < 12; ++i) acc[i] = (f32x4)0.f;

  for (int kc = 0; kc < 6; ++kc) {
    __syncthreads();
    for (int idx = tid; idx < 1536; idx += 256) {
      int row = idx >> 3, c8 = (idx & 7) * 8;
      *(uint4*)&wsh[row * 72 + c8] =
          *(const uint4*)(Wt + (size_t)(n0 + row) * 384 + kc * 64 + c8);
    }
    __syncthreads();
#pragma unroll
    for (int ks = 0; ks < 2; ++ks) {
      bf16x8 af = ldsfrag(&xs[rowm * 392 + kc * 64 + ks * 32 + g * 4]);
#pragma unroll
      for (int nf = 0; nf < 12; ++nf) {
        bf16x8 bf = ldsfrag(&wsh[(nf * 16 + ql) * 72 + ks * 32 + g * 4]);
        acc[nf] = __builtin_amdgcn_mfma_f32_16x16x32_bf16(af, bf, acc[nf], 0, 0, 0);
      }
    }
  }

  // Epilogue: C row = m0 + w*16 + g*4 + r, col = n0 + nf*16 + ql
  const int mrow = m0 + w * 16 + g * 4;
  const int bb = mrow >> 11, tt = mrow & 2047;
#pragma unroll
  for (int nf = 0; nf < 12; ++nf) {
    const int n = n0 + nf * 16 + ql;
    const int nn = n - mat * 384, h = nn >> 6, d = nn & 63;
    if (mat < 2) {
      u16* dst = (mat ? Kb : Qb) + ((size_t)(bb * H_ + h) * T_ + tt) * D_ + d;
#pragma unroll
      for (int r = 0; r < 4; ++r) dst[(size_t)r * D_] = (u16)f2bf(acc[nf][r]);
    } else {  // V stored transposed [B,H,D,T]; 4 consecutive t pack to uint2
      u16* dst = Vtb + ((size_t)(bb * H_ + h) * D_ + d) * T_ + tt;
      uint2 o; o.x = pk2(acc[nf][0], acc[nf][1]); o.y = pk2(acc[nf][2], acc[nf][3]);
      *(uint2*)dst = o;
    }
  }
}

// ---------------------------------------------------------------------------
// Flash attention (MFMA, swapped operands).
// S^T = mfma(K, Q): lane holds S[k = kb*16+g*4+r][q = lane&15] -> softmax is
// lane-local over 16 regs + shfl_xor(16,32).  O^T = mfma(V^T, P): lane holds
// O[q = lane&15][d = db*16+g*4+r] -> rescale and 1/l lane-local.
// Grid: B*H*32 blocks of 256 (4 waves x 16 q-rows). Heavy blocks first.
// ---------------------------------------------------------------------------
__global__ __launch_bounds__(256) void attn_mfma_kernel(
    const u16* __restrict__ Qb, const u16* __restrict__ Kb,
    const u16* __restrict__ Vtb, u16* __restrict__ attnb) {
  __shared__ u16 Qs[64 * 72], Ks[64 * 72], Vt[64 * 72];
  const int tid = threadIdx.x;
  const int bx = blockIdx.x;
  const int qi = 31 - (bx & 31);           // heavy-first for causal balance
  const int bh = bx >> 5;
  const int h = bh % H_, b = bh / H_;
  const int r0 = qi << 6;
  const size_t hb = (size_t)(b * H_ + h) * T_ * D_;   // K/Q base; also V^T base

  for (int idx = tid; idx < 512; idx += 256) {
    int row = idx >> 3, c8 = (idx & 7) * 8;
    *(uint4*)&Qs[row * 72 + c8] =
        *(const uint4*)(Qb + hb + (size_t)(r0 + row) * D_ + c8);
  }
  __syncthreads();

  const int l = tid & 63, w = tid >> 6, g = l >> 4, ql = l & 15;
  const bf16x8 qf0 = ldsfrag(&Qs[(w * 16 + ql) * 72 + g * 4]);
  const bf16x8 qf1 = ldsfrag(&Qs[(w * 16 + ql) * 72 + g * 4 + 32]);

  f32x4 oacc[4];
#pragma unroll
  for (int i = 0; i < 4; ++i) oacc[i] = (f32x4)0.f;
  float mrun = -1e30f, lrun = 0.f;

  for (int jt = 0; jt <= qi; ++jt) {
    __syncthreads();
    for (int idx = tid; idx < 512; idx += 256) {
      int row = idx >> 3, c8 = (idx & 7) * 8;
      *(uint4*)&Ks[row * 72 + c8] =
          *(const uint4*)(Kb + hb + (size_t)(jt * 64 + row) * D_ + c8);
      *(uint4*)&Vt[row * 72 + c8] =
          *(const uint4*)(Vtb + hb + (size_t)row * T_ + jt * 64 + c8);
    }
    __syncthreads();

    f32x4 sacc[4];
#pragma unroll
    for (int i = 0; i < 4; ++i) sacc[i] = (f32x4)0.f;
#pragma unroll
    for (int kb = 0; kb < 4; ++kb) {
      bf16x8 kf0 = ldsfrag(&Ks[(kb * 16 + ql) * 72 + g * 4]);
      sacc[kb] = __builtin_amdgcn_mfma_f32_16x16x32_bf16(kf0, qf0, sacc[kb], 0, 0, 0);
      bf16x8 kf1 = ldsfrag(&Ks[(kb * 16 + ql) * 72 + g * 4 + 32]);
      sacc[kb] = __builtin_amdgcn_mfma_f32_16x16x32_bf16(kf1, qf1, sacc[kb], 0, 0, 0);
    }

    float ps[16];
#pragma unroll
    for (int kb = 0; kb < 4; ++kb)
#pragma unroll
      for (int r = 0; r < 4; ++r) ps[kb * 4 + r] = sacc[kb][r] * 0.125f;

    if (jt == qi) {
      const int qloc = w * 16 + ql;
#pragma unroll
      for (int kb = 0; kb < 4; ++kb)
#pragma unroll
        for (int r = 0; r < 4; ++r)
          if (kb * 16 + g * 4 + r > qloc) ps[kb * 4 + r] = -1e30f;
    }

    float tm = ps[0];
#pragma unroll
    for (int i = 1; i < 16; ++i) tm = fmaxf(tm, ps[i]);
    tm = fmaxf(tm, __shfl_xor(tm, 16));
    tm = fmaxf(tm, __shfl_xor(tm, 32));
    const float mnew = fmaxf(mrun, tm);
    const float fsc = __expf(mrun - mnew);
    float rs = 0.f;
#pragma unroll
    for (int i = 0; i < 16; ++i) { ps[i] = __expf(ps[i] - mnew); rs += ps[i]; }
    rs += __shfl_xor(rs, 16);
    rs += __shfl_xor(rs, 32);
    lrun = lrun * fsc + rs;
    mrun = mnew;
#pragma unroll
    for (int i = 0; i < 4; ++i) oacc[i] *= fsc;

    // P -> bf16 B-frags in-register (k-map matches kappa)
    uint4 t0, t1;
    t0.x = pk2(ps[0], ps[1]);   t0.y = pk2(ps[2], ps[3]);
    t0.z = pk2(ps[4], ps[5]);   t0.w = pk2(ps[6], ps[7]);
    t1.x = pk2(ps[8], ps[9]);   t1.y = pk2(ps[10], ps[11]);
    t1.z = pk2(ps[12], ps[13]); t1.w = pk2(ps[14], ps[15]);
    const bf16x8 pf0 = u4bf(t0), pf1 = u4bf(t1);

#pragma unroll
    for (int db = 0; db < 4; ++db) {
      bf16x8 vf0 = ldsfrag(&Vt[(db * 16 + ql) * 72 + g * 4]);
      oacc[db] = __builtin_amdgcn_mfma_f32_16x16x32_bf16(vf0, pf0, oacc[db], 0, 0, 0);
      bf16x8 vf1 = ldsfrag(&Vt[(db * 16 + ql) * 72 + g * 4 + 32]);
      oacc[db] = __builtin_amdgcn_mfma_f32_16x16x32_bf16(vf1, pf1, oacc[db], 0, 0, 0);
    }
  }

  const float inv = 1.0f / lrun;
  const size_t rowbase =
      ((size_t)(b * T_ + r0 + w * 16 + ql)) * C_ + h * 64;
#pragma unroll
  for (int db = 0; db < 4; ++db) {
    uint2 o;
    o.x = pk2(oacc[db][0] * inv, oacc[db][1] * inv);
    o.y = pk2(oacc[db][2] * inv, oacc[db][3] * inv);
    *(uint2*)&attnb[rowbase + db * 16 + g * 4] = o;
  }
}

// ---------------------------------------------------------------------------
// Output projection (MFMA): attnb bf16 [16384x384] @ Wpt + bp -> out fp32.
// ---------------------------------------------------------------------------
__global__ __launch_bounds__(256) void proj_mfma_kernel(
    const u16* __restrict__ attnb, const u16* __restrict__ Wpt,
    const float* __restrict__ bp, float* __restrict__ out) {
  __shared__ u16 as_[64 * 392];
  __shared__ u16 wsh[192 * 72];
  const int tid = threadIdx.x;
  const int nt = blockIdx.x & 1, mt = blockIdx.x >> 1;
  const int m0 = mt * 64, n0 = nt * 192;

  for (int idx = tid; idx < 3072; idx += 256) {
    int row = idx / 48, c8 = (idx % 48) * 8;
    *(uint4*)&as_[row * 392 + c8] =
        *(const uint4*)(attnb + (size_t)(m0 + row) * C_ + c8);
  }
  __syncthreads();

  const int l = tid & 63, w = tid >> 6, g = l >> 4, ql = l & 15;
  const int rowm = w * 16 + ql;
  f32x4 acc[12];
#pragma unroll
  for (int i = 0; i < 12; ++i) acc[i] = (f32x4)0.f;

  for (int kc = 0; kc < 6; ++kc) {
    __syncthreads();
    for (int idx = tid; idx < 1536; idx += 256) {
      int row = idx >> 3, c8 = (idx & 7) * 8;
      *(uint4*)&wsh[row * 72 + c8] =
          *(const uint4*)(Wpt + (size_t)(n0 + row) * 384 + kc * 64 + c8);
    }
    __syncthreads();
#pragma unroll
    for (int ks = 0; ks < 2; ++ks) {
      bf16x8 af = ldsfrag(&as_[rowm * 392 + kc * 64 + ks * 32 + g * 4]);
#pragma unroll
      for (int nf = 0; nf < 12; ++nf) {
        bf16x8 bf = ldsfrag(&wsh[(nf * 16 + ql) * 72 + ks * 32 + g * 4]);
        acc[nf] = __builtin_amdgcn_mfma_f32_16x16x32_bf16(af, bf, acc[nf], 0, 0, 0);
      }
    }
  }

  const int mrow = m0 + w * 16 + g * 4;
#pragma unroll
  for (int nf = 0; nf < 12; ++nf) {
    const int n = n0 + nf * 16 + ql;
    const float bias = bp[n];
#pragma unroll
    for (int r = 0; r < 4; ++r)
      out[(size_t)(mrow + r) * C_ + n] = acc[nf][r] + bias;
  }
}

// ---------------------------------------------------------------------------
extern "C" void kernel_launch(void* const* d_in, const int* in_sizes, int n_in,
                              void* d_out, int out_size, void* d_ws, size_t ws_size,
                              hipStream_t stream) {
  (void)in_sizes; (void)n_in; (void)out_size; (void)ws_size;
  const float* x  = (const float*)d_in[0];
  const float* Wq = (const float*)d_in[1];
  const float* Wk = (const float*)d_in[2];
  const float* Wv = (const float*)d_in[3];
  const float* Wp = (const float*)d_in[4];
  const float* bp = (const float*)d_in[5];
  float* out = (float*)d_out;

  // ws (u16 units): Wt 442368 | Wpt 147456 | Qb,Kb,Vtb 6291456 ea | attnb 6291456
  u16* Wt   = (u16*)d_ws;
  u16* Wpt  = Wt + 442368;
  u16* Qb   = Wpt + 147456;
  u16* Kb   = Qb + 6291456;
  u16* Vtb  = Kb + 6291456;
  u16* attnb = Vtb + 6291456;

  convert_kernel<<<576, 256, 0, stream>>>(Wq, Wk, Wv, Wp, Wt, Wpt);
  qkv_mfma_kernel<<<(16384 / 64) * 6, 256, 0, stream>>>(x, Wt, Qb, Kb, Vtb);
  attn_mfma_kernel<<<8 * H_ * 32, 256, 0, stream>>>(Qb, Kb, Vtb, attnb);
  proj_mfma_kernel<<<(16384 / 64) * 2, 256, 0, stream>>>(attnb, Wpt, bp, out);
}

// Round 3
// 180.601 us; speedup vs baseline: 10.5611x; 1.4619x over previous
//
#include <hip/hip_runtime.h>
#include <hip/hip_bf16.h>

// B=8, T=2048, C=384, H=6, Dh=64
constexpr int T_ = 2048;
constexpr int C_ = 384;
constexpr int H_ = 6;
constexpr int D_ = 64;

typedef unsigned int u32;
typedef unsigned short u16;
typedef __attribute__((ext_vector_type(4))) float f32x4;
typedef __attribute__((ext_vector_type(16))) float f32x16;
typedef __attribute__((ext_vector_type(8))) short bf16x8;
typedef __attribute__((ext_vector_type(4))) short bf16x4;

__device__ __forceinline__ u32 f2bf(float f) {
  u32 u = __float_as_uint(f);
  return (u + 0x7FFFu + ((u >> 16) & 1u)) >> 16;  // RNE
}
__device__ __forceinline__ u32 pk2(float a, float b) {
  return f2bf(a) | (f2bf(b) << 16);
}
// packed f32->bf16x2 via v_cvt_pk_bf16_f32 (compiler-emitted)
__device__ __forceinline__ u32 pkcvt(float a, float b) {
  __hip_bfloat162 h = __float22bfloat162_rn(float2{a, b});
  return *(u32*)&h;
}

// ---------------------------------------------------------------------------
// Convert weights to bf16, TRANSPOSED [n][k].
// ---------------------------------------------------------------------------
__global__ __launch_bounds__(256) void convert_kernel(
    const float* __restrict__ Wq, const float* __restrict__ Wk,
    const float* __restrict__ Wv, const float* __restrict__ Wp,
    u16* __restrict__ Wt, u16* __restrict__ Wpt) {
  int id = blockIdx.x * 256 + threadIdx.x;
  if (id < 110592) {                       // Wt: 1152*384/4
    int n = id / 96, c0 = (id % 96) * 4;
    int mat = n / 384, nn = n % 384, h = nn >> 6, d = nn & 63;
    const float* W = (mat == 0) ? Wq : ((mat == 1) ? Wk : Wv);
    const float* s = W + (size_t)(h * C_ + c0) * D_ + d;
    uint2 o; o.x = pk2(s[0], s[64]); o.y = pk2(s[128], s[192]);
    *(uint2*)&Wt[(size_t)n * 384 + c0] = o;
  } else {                                 // Wpt: 384*384/4
    int id2 = id - 110592;
    int n = id2 / 96, c0 = (id2 % 96) * 4;
    const float* s = Wp + (size_t)c0 * C_ + n;
    uint2 o; o.x = pk2(s[0], s[384]); o.y = pk2(s[768], s[1152]);
    *(uint2*)&Wpt[(size_t)n * 384 + c0] = o;
  }
}

// ---------------------------------------------------------------------------
// QKV GEMM (MFMA 16x16x32, contiguous kappa -> single ds_read_b128 frags).
// ---------------------------------------------------------------------------
__global__ __launch_bounds__(256) void qkv_mfma_kernel(
    const float* __restrict__ x, const u16* __restrict__ Wt,
    u16* __restrict__ Qb, u16* __restrict__ Kb, u16* __restrict__ Vtb) {
  __shared__ u16 xs[64 * 392];   // 392 = 49 granules (odd) -> conflict-free
  __shared__ u16 wsh[192 * 72];  // 72 = 9 granules (odd)
  const int tid = threadIdx.x;
  const int nt = blockIdx.x % 6, mt = blockIdx.x / 6;
  const int m0 = mt * 64, n0 = nt * 192, mat = nt >> 1;

  for (int idx = tid; idx < 6144; idx += 256) {
    int row = idx / 96, c4 = (idx % 96) * 4;
    f32x4 v = *(const f32x4*)(x + (size_t)(m0 + row) * C_ + c4);
    uint2 o; o.x = pk2(v[0], v[1]); o.y = pk2(v[2], v[3]);
    *(uint2*)&xs[row * 392 + c4] = o;
  }
  __syncthreads();

  const int l = tid & 63, w = tid >> 6, g = l >> 4, ql = l & 15;
  const int rowm = w * 16 + ql;
  f32x4 acc[12];
#pragma unroll
  for (int i = 0; i < 12; ++i) acc[i] = (f32x4)0.f;

  for (int kc = 0; kc < 6; ++kc) {
    __syncthreads();
    for (int idx = tid; idx < 1536; idx += 256) {
      int row = idx >> 3, c8 = (idx & 7) * 8;
      *(uint4*)&wsh[row * 72 + c8] =
          *(const uint4*)(Wt + (size_t)(n0 + row) * 384 + kc * 64 + c8);
    }
    __syncthreads();
#pragma unroll
    for (int ks = 0; ks < 2; ++ks) {
      bf16x8 af = *(const bf16x8*)&xs[rowm * 392 + kc * 64 + ks * 32 + g * 8];
#pragma unroll
      for (int nf = 0; nf < 12; ++nf) {
        bf16x8 bf = *(const bf16x8*)&wsh[(nf * 16 + ql) * 72 + ks * 32 + g * 8];
        acc[nf] = __builtin_amdgcn_mfma_f32_16x16x32_bf16(af, bf, acc[nf], 0, 0, 0);
      }
    }
  }

  const int mrow = m0 + w * 16 + g * 4;
  const int bb = mrow >> 11, tt = mrow & 2047;
#pragma unroll
  for (int nf = 0; nf < 12; ++nf) {
    const int n = n0 + nf * 16 + ql;
    const int nn = n - mat * 384, h = nn >> 6, d = nn & 63;
    if (mat < 2) {
      u16* dst = (mat ? Kb : Qb) + ((size_t)(bb * H_ + h) * T_ + tt) * D_ + d;
#pragma unroll
      for (int r = 0; r < 4; ++r) dst[(size_t)r * D_] = (u16)f2bf(acc[nf][r]);
    } else {  // V transposed [B,H,D,T]
      u16* dst = Vtb + ((size_t)(bb * H_ + h) * D_ + d) * T_ + tt;
      uint2 o; o.x = pk2(acc[nf][0], acc[nf][1]); o.y = pk2(acc[nf][2], acc[nf][3]);
      *(uint2*)dst = o;
    }
  }
}

// ---------------------------------------------------------------------------
// Flash attention, 32x32x16 MFMA, swapped operands, double-buffered LDS.
// Block: 4 waves x 32 q-rows = 128 q. KVBLK=64. XOR-swizzled K/V tiles.
// S^T = mfma(K, Q): lane(hi,l31) holds S[k=kc*32+(r&3)+8*(r>>2)+4hi][q=l31].
// O^T = mfma(V^T, P): kappa_O(hi,j)=(j&3)+8*(j>>2)+4hi == C/D layout -> P
// repack is register-local. Softmax in-register, exp2-domain, defer-max.
// ---------------------------------------------------------------------------
__global__ __launch_bounds__(256) void attn_mfma_kernel(
    const u16* __restrict__ Qb, const u16* __restrict__ Kb,
    const u16* __restrict__ Vtb, u16* __restrict__ attnb) {
  __shared__ u16 Ks[2][64 * 64];
  __shared__ u16 Vs[2][64 * 64];
  const int tid = threadIdx.x;
  const int bx = blockIdx.x;
  const int qb = 15 - (bx / 48);           // heavy-first (LPT greedy)
  const int bh = bx % 48;
  const int h = bh % H_, b = bh / H_;
  const int Q0 = qb * 128;
  const int nt = 2 * qb + 2;
  const size_t hb = (size_t)bh * T_ * D_;  // base for K/Q [T][D] and V^T [D][T]

  const int l = tid & 63, w = tid >> 6;
  const int hi = l >> 5, l31 = l & 31;
  const int qw0 = Q0 + w * 32;
  const int qrow = qw0 + l31;
  const int qwmax = qw0 + 31;

  // staging geometry: 512 granules of 16B per 64x64 tile, 2 per thread
  const int srow0 = tid >> 3, sc16 = tid & 7;
  const int srow1 = srow0 + 32;
  const int sw0 = srow0 * 64 + ((sc16 * 8) ^ ((srow0 & 7) * 8));
  const int sw1 = srow1 * 64 + ((sc16 * 8) ^ ((srow1 & 7) * 8));

  // Q fragments in registers: c = cs*16 + 8*hi + j
  bf16x8 qf[4];
  {
    const u16* qg = Qb + hb + (size_t)qrow * D_ + hi * 8;
#pragma unroll
    for (int cs = 0; cs < 4; ++cs) qf[cs] = *(const bf16x8*)(qg + cs * 16);
  }

  // prologue: stage tile 0
  {
    uint4 k0 = *(const uint4*)(Kb + hb + (size_t)srow0 * D_ + sc16 * 8);
    uint4 k1 = *(const uint4*)(Kb + hb + (size_t)srow1 * D_ + sc16 * 8);
    uint4 v0 = *(const uint4*)(Vtb + hb + (size_t)srow0 * T_ + sc16 * 8);
    uint4 v1 = *(const uint4*)(Vtb + hb + (size_t)srow1 * T_ + sc16 * 8);
    *(uint4*)&Ks[0][sw0] = k0; *(uint4*)&Ks[0][sw1] = k1;
    *(uint4*)&Vs[0][sw0] = v0; *(uint4*)&Vs[0][sw1] = v1;
  }
  __syncthreads();

  f32x16 oacc[2];
  oacc[0] = (f32x16)0.f; oacc[1] = (f32x16)0.f;
  float mrun = -1e30f, lrun = 0.f;
  int cur = 0;
  const int swzA = (l31 & 7) * 8;
  constexpr float SC = 0.18033688011112042f;  // 0.125 * log2(e)

  for (int jt = 0; jt < nt; ++jt) {
    const bool have_next = (jt + 1) < nt;
    uint4 kn0, kn1, vn0, vn1;
    if (have_next) {  // T14: issue early, write after barrier
      const size_t kbase = hb + (size_t)(jt + 1) * 64 * D_;
      kn0 = *(const uint4*)(Kb + kbase + (size_t)srow0 * D_ + sc16 * 8);
      kn1 = *(const uint4*)(Kb + kbase + (size_t)srow1 * D_ + sc16 * 8);
      const size_t vbase = hb + (size_t)(jt + 1) * 64;
      vn0 = *(const uint4*)(Vtb + vbase + (size_t)srow0 * T_ + sc16 * 8);
      vn1 = *(const uint4*)(Vtb + vbase + (size_t)srow1 * T_ + sc16 * 8);
    }

    if (jt * 64 <= qwmax) {  // wave-uniform: this wave has unmasked work
      // ---- S phase ----
      f32x16 sacc[2];
      sacc[0] = (f32x16)0.f; sacc[1] = (f32x16)0.f;
      __builtin_amdgcn_s_setprio(1);
#pragma unroll
      for (int kc = 0; kc < 2; ++kc) {
#pragma unroll
        for (int cs = 0; cs < 4; ++cs) {
          bf16x8 kf = *(const bf16x8*)
              &Ks[cur][(kc * 32 + l31) * 64 + ((cs * 16 + 8 * hi) ^ swzA)];
          sacc[kc] = __builtin_amdgcn_mfma_f32_32x32x16_bf16(kf, qf[cs], sacc[kc], 0, 0, 0);
        }
      }
      __builtin_amdgcn_s_setprio(0);

      float ps[2][16];
#pragma unroll
      for (int kc = 0; kc < 2; ++kc)
#pragma unroll
        for (int r = 0; r < 16; ++r) ps[kc][r] = sacc[kc][r] * SC;

      if (jt * 64 + 63 > qwmax - 31 + 31) { /* placeholder never taken */ }
      if ((jt + 1) * 64 > qw0) {  // diagonal region: element mask
#pragma unroll
        for (int kc = 0; kc < 2; ++kc)
#pragma unroll
          for (int r = 0; r < 16; ++r) {
            const int kglob = jt * 64 + kc * 32 + (r & 3) + 8 * (r >> 2) + 4 * hi;
            if (kglob > qrow) ps[kc][r] = -1e30f;
          }
      }

      float tm = ps[0][0];
#pragma unroll
      for (int kc = 0; kc < 2; ++kc)
#pragma unroll
        for (int r = 0; r < 16; ++r) if (kc || r) tm = fmaxf(tm, ps[kc][r]);
      tm = fmaxf(tm, __shfl_xor(tm, 32));

      const bool defer = __all(tm <= mrun + 10.0f);  // T13 (log2 units)
      if (!defer) {
        const float mnew = fmaxf(mrun, tm);
        const float fsc = exp2f(mrun - mnew);
        oacc[0] *= fsc; oacc[1] *= fsc;
        lrun *= fsc;
        mrun = mnew;
      }
      float rs = 0.f;
#pragma unroll
      for (int kc = 0; kc < 2; ++kc)
#pragma unroll
        for (int r = 0; r < 16; ++r) {
          ps[kc][r] = exp2f(ps[kc][r] - mrun);
          rs += ps[kc][r];
        }
      rs += __shfl_xor(rs, 32);
      lrun += rs;

      // P -> bf16 B-frags, register-local: pf[ks] slot j = ps[ks>>1][(ks&1)*8+j]
      u32 pw[4][4];
#pragma unroll
      for (int ks = 0; ks < 4; ++ks)
#pragma unroll
        for (int wd = 0; wd < 4; ++wd)
          pw[ks][wd] = pkcvt(ps[ks >> 1][(ks & 1) * 8 + 2 * wd],
                             ps[ks >> 1][(ks & 1) * 8 + 2 * wd + 1]);

      // ---- O phase ----
      __builtin_amdgcn_s_setprio(1);
#pragma unroll
      for (int dc = 0; dc < 2; ++dc) {
#pragma unroll
        for (int ks = 0; ks < 4; ++ks) {
          const int rb = (dc * 32 + l31) * 64;
          bf16x4 v0 = *(const bf16x4*)&Vs[cur][rb + ((ks * 16 + 4 * hi) ^ swzA)];
          bf16x4 v1 = *(const bf16x4*)&Vs[cur][rb + ((ks * 16 + 4 * hi + 8) ^ swzA)];
          bf16x8 vf;
          *(bf16x4*)&vf = v0; *((bf16x4*)&vf + 1) = v1;
          bf16x8 pf;
          *(uint4*)&pf = make_uint4(pw[ks][0], pw[ks][1], pw[ks][2], pw[ks][3]);
          oacc[dc] = __builtin_amdgcn_mfma_f32_32x32x16_bf16(vf, pf, oacc[dc], 0, 0, 0);
        }
      }
      __builtin_amdgcn_s_setprio(0);
    }

    __syncthreads();
    if (have_next) {
      *(uint4*)&Ks[cur ^ 1][sw0] = kn0; *(uint4*)&Ks[cur ^ 1][sw1] = kn1;
      *(uint4*)&Vs[cur ^ 1][sw0] = vn0; *(uint4*)&Vs[cur ^ 1][sw1] = vn1;
    }
    __syncthreads();
    cur ^= 1;
  }

  // epilogue: O/l -> attnb[b, q, h*64 + d], d = dc*32 + 8*g4 + 4*hi + i
  const float inv = 1.0f / lrun;
  u16* obase = attnb + ((size_t)(b * T_ + qrow)) * C_ + h * 64;
#pragma unroll
  for (int dc = 0; dc < 2; ++dc)
#pragma unroll
    for (int g4 = 0; g4 < 4; ++g4) {
      uint2 o;
      o.x = pkcvt(oacc[dc][g4 * 4 + 0] * inv, oacc[dc][g4 * 4 + 1] * inv);
      o.y = pkcvt(oacc[dc][g4 * 4 + 2] * inv, oacc[dc][g4 * 4 + 3] * inv);
      *(uint2*)(obase + dc * 32 + 8 * g4 + 4 * hi) = o;
    }
}

// ---------------------------------------------------------------------------
// Output projection (MFMA): attnb bf16 @ Wpt + bp -> out fp32.
// ---------------------------------------------------------------------------
__global__ __launch_bounds__(256) void proj_mfma_kernel(
    const u16* __restrict__ attnb, const u16* __restrict__ Wpt,
    const float* __restrict__ bp, float* __restrict__ out) {
  __shared__ u16 as_[64 * 392];
  __shared__ u16 wsh[192 * 72];
  const int tid = threadIdx.x;
  const int nt = blockIdx.x & 1, mt = blockIdx.x >> 1;
  const int m0 = mt * 64, n0 = nt * 192;

  for (int idx = tid; idx < 3072; idx += 256) {
    int row = idx / 48, c8 = (idx % 48) * 8;
    *(uint4*)&as_[row * 392 + c8] =
        *(const uint4*)(attnb + (size_t)(m0 + row) * C_ + c8);
  }
  __syncthreads();

  const int l = tid & 63, w = tid >> 6, g = l >> 4, ql = l & 15;
  const int rowm = w * 16 + ql;
  f32x4 acc[12];
#pragma unroll
  for (int i = 0; i < 12; ++i) acc[i] = (f32x4)0.f;

  for (int kc = 0; kc < 6; ++kc) {
    __syncthreads();
    for (int idx = tid; idx < 1536; idx += 256) {
      int row = idx >> 3, c8 = (idx & 7) * 8;
      *(uint4*)&wsh[row * 72 + c8] =
          *(const uint4*)(Wpt + (size_t)(n0 + row) * 384 + kc * 64 + c8);
    }
    __syncthreads();
#pragma unroll
    for (int ks = 0; ks < 2; ++ks) {
      bf16x8 af = *(const bf16x8*)&as_[rowm * 392 + kc * 64 + ks * 32 + g * 8];
#pragma unroll
      for (int nf = 0; nf < 12; ++nf) {
        bf16x8 bf = *(const bf16x8*)&wsh[(nf * 16 + ql) * 72 + ks * 32 + g * 8];
        acc[nf] = __builtin_amdgcn_mfma_f32_16x16x32_bf16(af, bf, acc[nf], 0, 0, 0);
      }
    }
  }

  const int mrow = m0 + w * 16 + g * 4;
#pragma unroll
  for (int nf = 0; nf < 12; ++nf) {
    const int n = n0 + nf * 16 + ql;
    const float bias = bp[n];
#pragma unroll
    for (int r = 0; r < 4; ++r)
      out[(size_t)(mrow + r) * C_ + n] = acc[nf][r] + bias;
  }
}

// ---------------------------------------------------------------------------
extern "C" void kernel_launch(void* const* d_in, const int* in_sizes, int n_in,
                              void* d_out, int out_size, void* d_ws, size_t ws_size,
                              hipStream_t stream) {
  (void)in_sizes; (void)n_in; (void)out_size; (void)ws_size;
  const float* x  = (const float*)d_in[0];
  const float* Wq = (const float*)d_in[1];
  const float* Wk = (const float*)d_in[2];
  const float* Wv = (const float*)d_in[3];
  const float* Wp = (const float*)d_in[4];
  const float* bp = (const float*)d_in[5];
  float* out = (float*)d_out;

  u16* Wt   = (u16*)d_ws;
  u16* Wpt  = Wt + 442368;
  u16* Qb   = Wpt + 147456;
  u16* Kb   = Qb + 6291456;
  u16* Vtb  = Kb + 6291456;
  u16* attnb = Vtb + 6291456;

  convert_kernel<<<576, 256, 0, stream>>>(Wq, Wk, Wv, Wp, Wt, Wpt);
  qkv_mfma_kernel<<<(16384 / 64) * 6, 256, 0, stream>>>(x, Wt, Qb, Kb, Vtb);
  attn_mfma_kernel<<<768, 256, 0, stream>>>(Qb, Kb, Vtb, attnb);
  proj_mfma_kernel<<<(16384 / 64) * 2, 256, 0, stream>>>(attnb, Wpt, bp, out);
}